// Round 3
// baseline (256.795 us; speedup 1.0000x reference)
//
#include <hip/hip_runtime.h>
#include <hip/hip_bf16.h>

typedef _Float16 f16;
typedef __attribute__((ext_vector_type(2))) _Float16 f16x2;
typedef __attribute__((ext_vector_type(8))) _Float16 f16x8;
typedef __attribute__((ext_vector_type(16))) float f32x16;

#define BNSCL 0.9999950000375f   /* 1/sqrt(1+1e-5) */

// ---------------------------------------------------------------------------
// Kernel 1: per-point scores MLP + softmax (weights in LDS, 2 pts/thread),
// output f16x8 per point. Fused: blocks < 256 also build wbtA = weight bank
// in MFMA A-fragment order, f16:
//   wbtA[((ot*64 + ks)*64 + lane)*8 + j] = wb[c'][m=j][o]
//   with c' = ks*2 + (lane>>5), o = ot*32 + (lane&31).
// ---------------------------------------------------------------------------
__global__ __launch_bounds__(256) void k_scores(
    const float* __restrict__ xyz,
    const float* __restrict__ w1, const float* __restrict__ g1, const float* __restrict__ be1,
    const float* __restrict__ w2, const float* __restrict__ g2, const float* __restrict__ be2,
    const float* __restrict__ w3, const float* __restrict__ g3, const float* __restrict__ be3,
    const float* __restrict__ w4, const float* __restrict__ b4,
    const float* __restrict__ wb, f16* __restrict__ wbtA,
    f16* __restrict__ scores)
{
    __shared__ float lw[856];
    const int tid = threadIdx.x;

    // fused weight-bank fragment-order transpose (1 elem/thread, blocks 0-255)
    if (blockIdx.x < 256) {
        int idx = blockIdx.x * 256 + tid;       // 0..65535
        int j    = idx & 7;
        int lane = (idx >> 3) & 63;
        int ks   = (idx >> 9) & 63;
        int ot   = idx >> 15;
        int cp   = ks * 2 + (lane >> 5);        // 0..127
        int o    = ot * 32 + (lane & 31);
        wbtA[idx] = (f16)wb[(cp * 8 + j) * 64 + o];
    }

    if (tid < 112) lw[tid] = w1[tid];
    lw[112 + tid] = w2[tid];
    lw[368 + tid] = w3[tid];
    if (tid < 128) lw[624 + tid] = w4[tid];
    if (tid < 8)   lw[752 + tid] = b4[tid];
    if (tid < 16) {
        lw[760 + tid] = g1[tid] * BNSCL;  lw[776 + tid] = be1[tid];
        lw[792 + tid] = g2[tid] * BNSCL;  lw[808 + tid] = be2[tid];
        lw[824 + tid] = g3[tid] * BNSCL;  lw[840 + tid] = be3[tid];
    }
    __syncthreads();

    float in7[2][7], h1[2][16], h2[2][16], s[2][8];

#pragma unroll
    for (int q = 0; q < 2; ++q) {
        int g = blockIdx.x * 512 + q * 256 + tid;
        int b = g >> 15;
        int p = g & 32767;
        int pc = p & ~31;
        const float* xb = xyz + (size_t)b * 98304;
        float cx = xb[pc], cy = xb[32768 + pc], cz = xb[65536 + pc];
        float dx = xb[p] - cx, dy = xb[32768 + p] - cy, dz = xb[65536 + p] - cz;
        in7[q][0] = cx; in7[q][1] = cy; in7[q][2] = cz;
        in7[q][3] = dx; in7[q][4] = dy; in7[q][5] = dz;
        in7[q][6] = sqrtf(dx * dx + dy * dy + dz * dz);
    }

#pragma unroll
    for (int o = 0; o < 16; ++o) {
        float a0 = 0.f, a1 = 0.f;
#pragma unroll
        for (int c = 0; c < 7; ++c) {
            float w = lw[o * 7 + c];
            a0 += w * in7[0][c]; a1 += w * in7[1][c];
        }
        float gs = lw[760 + o], bb = lw[776 + o];
        h1[0][o] = fmaxf(a0 * gs + bb, 0.f);
        h1[1][o] = fmaxf(a1 * gs + bb, 0.f);
    }
#pragma unroll
    for (int o = 0; o < 16; ++o) {
        float a0 = 0.f, a1 = 0.f;
#pragma unroll
        for (int c = 0; c < 16; ++c) {
            float w = lw[112 + o * 16 + c];
            a0 += w * h1[0][c]; a1 += w * h1[1][c];
        }
        float gs = lw[792 + o], bb = lw[808 + o];
        h2[0][o] = fmaxf(a0 * gs + bb, 0.f);
        h2[1][o] = fmaxf(a1 * gs + bb, 0.f);
    }
#pragma unroll
    for (int o = 0; o < 16; ++o) {
        float a0 = 0.f, a1 = 0.f;
#pragma unroll
        for (int c = 0; c < 16; ++c) {
            float w = lw[368 + o * 16 + c];
            a0 += w * h2[0][c]; a1 += w * h2[1][c];
        }
        float gs = lw[824 + o], bb = lw[840 + o];
        h1[0][o] = fmaxf(a0 * gs + bb, 0.f);
        h1[1][o] = fmaxf(a1 * gs + bb, 0.f);
    }
#pragma unroll
    for (int o = 0; o < 8; ++o) {
        float bb = lw[752 + o];
        float a0 = bb, a1 = bb;
#pragma unroll
        for (int c = 0; c < 16; ++c) {
            float w = lw[624 + o * 16 + c];
            a0 += w * h1[0][c]; a1 += w * h1[1][c];
        }
        s[0][o] = a0; s[1][o] = a1;
    }

#pragma unroll
    for (int q = 0; q < 2; ++q) {
        int g = blockIdx.x * 512 + q * 256 + tid;
        float mx = s[q][0];
#pragma unroll
        for (int i = 1; i < 8; ++i) mx = fmaxf(mx, s[q][i]);
        float sum = 0.f;
#pragma unroll
        for (int i = 0; i < 8; ++i) { s[q][i] = __expf(s[q][i] - mx); sum += s[q][i]; }
        float inv = 1.f / sum;
        f16x8 o8;
#pragma unroll
        for (int i = 0; i < 8; ++i) o8[i] = (f16)(s[q][i] * inv);
        *(f16x8*)(scores + (size_t)g * 8) = o8;
    }
}

// ---------------------------------------------------------------------------
// Kernel 2: main einsum, 32x32x16 f16 MFMA. Weights resident in LDS (64 KB),
// staged ONCE, one barrier.
// THIS ROUND: block = 1024 thr (16 waves), grid = 512. Round-2 counters
// showed OccupancyPercent ~30 (64 KB LDS -> 2 blocks x 8 waves = 16 waves/CU
// cap) with per-iter serial latency ~2000 cyc — latency-bound on feat loads,
// and ILP-depth-4 alone couldn't cover it at 4 waves/SIMD. Sharing one LDS
// weight image among 16 waves doubles residency to 32 waves/CU (100% cap):
// TLP-based latency hiding that doesn't depend on compiler scheduling.
// Also halves the number of blocks re-staging the same 64 KB.
// Distance-4 register prefetch kept (literal-index macro steps, rule #20);
// prefetch groups 0..3 issued BEFORE weight staging. ot = bx>>8 keeps both
// ot-halves of the same points on the same XCD (256 % 8 == 0).
// ---------------------------------------------------------------------------
__global__ __launch_bounds__(1024, 8) void k_main(
    const float* __restrict__ feat,
    const f16* __restrict__ scores,
    const f16* __restrict__ wbtA,
    const float* __restrict__ bn_g, const float* __restrict__ bn_b,
    float* __restrict__ out)
{
    __shared__ __align__(16) f16 lwb[32768];    // 64 KB

    const int tid  = threadIdx.x;
    const int lane = tid & 63;
    const int wave = tid >> 6;          // 0..15
    const int l31  = lane & 31;
    const int lh   = lane >> 5;         // 0..1

    const int ot = blockIdx.x >> 8;             // 0..1 (o-tile half)
    const int g  = blockIdx.x & 255;            // point-group
    const int pblock = g * 1024;                // global point base
    const int b    = pblock >> 15;
    const int pt0  = (pblock & 32767) + wave * 64;   // within-batch, 32-aligned
    const int pc0  = pt0 + l31;
    const int pc1  = pc0 + 32;

    const float* fb  = feat + (size_t)b * 2097152;   // (64, 32768)
    const float* frb = fb + ((size_t)lh << 15);      // this half-wave's row base
    // channel-pair stride per kk = 2 rows = 65536 floats = (1<<16)

    // ---- issue feat prefetch (distance 4) BEFORE weight staging ----
    float pA[4], pB[4], pC[4], pD[4];
#pragma unroll
    for (int d = 0; d < 4; ++d) {
        const float* fr = frb + ((size_t)d << 16);
        pA[d] = fr[pc0]; pB[d] = fr[pc1]; pC[d] = fr[pt0]; pD[d] = fr[pt0 + 32];
    }

    const int gpt = pblock + wave * 64 + l31;
    f16x8 sv0 = *(const f16x8*)(scores + (size_t)gpt * 8);
    f16x8 sv1 = *(const f16x8*)(scores + (size_t)(gpt + 32) * 8);

    // ---- stage this ot's 64 KB of fragment-ordered weights into LDS ----
    const f16* src = wbtA + ((size_t)ot << 15);      // 32768 f16
#pragma unroll
    for (int it = 0; it < 4; ++it) {
        int idx = it * 1024 + tid;                   // 0..4095 16B-chunks
        *(int4*)&lwb[idx << 3] = *(const int4*)&src[idx << 3];
    }
    __syncthreads();

    const f16x2 s0a = {sv0[0], sv0[1]}, s0b = {sv0[2], sv0[3]},
                s0c = {sv0[4], sv0[5]}, s0d = {sv0[6], sv0[7]};
    const f16x2 s1a = {sv1[0], sv1[1]}, s1b = {sv1[2], sv1[3]},
                s1c = {sv1[4], sv1[5]}, s1d = {sv1[6], sv1[7]};

    f32x16 acc0 = {}, acc1 = {};

    const f16* Alds = lwb + (lane << 3);             // lane's 16B slot

#define KSTEP(kk, RELOAD)                                                      \
    {                                                                          \
        const int d_ = (kk) & 3;                                               \
        float fv0 = pA[d_], fv1 = pB[d_], fc0 = pC[d_], fc1 = pD[d_];          \
        if (RELOAD) {                                                          \
            const float* fr_ = frb + ((size_t)((kk) + 4) << 16);               \
            pA[d_] = fr_[pc0]; pB[d_] = fr_[pc1];                              \
            pC[d_] = fr_[pt0]; pD[d_] = fr_[pt0 + 32];                         \
        }                                                                      \
        f16x8 aD = *(const f16x8*)(Alds + ((size_t)(kk) << 9));                \
        f16x8 aR = *(const f16x8*)(Alds + ((size_t)((kk) + 32) << 9));         \
        f16 hR0 = (f16)fv0,          hR1 = (f16)fv1;                           \
        f16 hD0 = (f16)(fv0 - fc0),  hD1 = (f16)(fv1 - fc1);                   \
        f16x2 fR0 = {hR0, hR0}, fR1 = {hR1, hR1};                              \
        f16x2 fD0 = {hD0, hD0}, fD1 = {hD1, hD1};                              \
        f16x2 d0a = fD0 * s0a, d0b = fD0 * s0b, d0c = fD0 * s0c, d0d = fD0 * s0d; \
        f16x2 d1a = fD1 * s1a, d1b = fD1 * s1b, d1c = fD1 * s1c, d1d = fD1 * s1d; \
        f16x2 r0a = fR0 * s0a, r0b = fR0 * s0b, r0c = fR0 * s0c, r0d = fR0 * s0d; \
        f16x2 r1a = fR1 * s1a, r1b = fR1 * s1b, r1c = fR1 * s1c, r1d = fR1 * s1d; \
        f16x8 bD0 = {d0a[0],d0a[1],d0b[0],d0b[1],d0c[0],d0c[1],d0d[0],d0d[1]}; \
        f16x8 bD1 = {d1a[0],d1a[1],d1b[0],d1b[1],d1c[0],d1c[1],d1d[0],d1d[1]}; \
        f16x8 bR0 = {r0a[0],r0a[1],r0b[0],r0b[1],r0c[0],r0c[1],r0d[0],r0d[1]}; \
        f16x8 bR1 = {r1a[0],r1a[1],r1b[0],r1b[1],r1c[0],r1c[1],r1d[0],r1d[1]}; \
        acc0 = __builtin_amdgcn_mfma_f32_32x32x16_f16(aD, bD0, acc0, 0, 0, 0); \
        acc1 = __builtin_amdgcn_mfma_f32_32x32x16_f16(aD, bD1, acc1, 0, 0, 0); \
        acc0 = __builtin_amdgcn_mfma_f32_32x32x16_f16(aR, bR0, acc0, 0, 0, 0); \
        acc1 = __builtin_amdgcn_mfma_f32_32x32x16_f16(aR, bR1, acc1, 0, 0, 0); \
    }

#define KS4(b0, R) KSTEP(b0, R) KSTEP((b0)+1, R) KSTEP((b0)+2, R) KSTEP((b0)+3, R)
    KS4(0, 1)  KS4(4, 1)  KS4(8, 1)  KS4(12, 1)
    KS4(16, 1) KS4(20, 1) KS4(24, 1) KS4(28, 0)
#undef KS4
#undef KSTEP

    // ---------------- epilogue: BN + ReLU + coalesced store ------------------
    // C layout: col = lane&31, row = (r&3) + 8*(r>>2) + 4*lh
#pragma unroll
    for (int r = 0; r < 16; ++r) {
        int o = ot * 32 + (r & 3) + ((r >> 2) << 3) + (lh << 2);
        float gs = bn_g[o] * BNSCL, bb = bn_b[o];
        size_t row = (size_t)(b * 64 + o) << 15;
        out[row + pc0] = fmaxf(acc0[r] * gs + bb, 0.f);
        out[row + pc1] = fmaxf(acc1[r] * gs + bb, 0.f);
    }
}

// ---------------------------------------------------------------------------
extern "C" void kernel_launch(void* const* d_in, const int* in_sizes, int n_in,
                              void* d_out, int out_size, void* d_ws, size_t ws_size,
                              hipStream_t stream)
{
    const float* features = (const float*)d_in[0];
    const float* xyz      = (const float*)d_in[1];
    const float* w1  = (const float*)d_in[2];
    const float* g1  = (const float*)d_in[3];
    const float* be1 = (const float*)d_in[4];
    const float* w2  = (const float*)d_in[5];
    const float* g2  = (const float*)d_in[6];
    const float* be2 = (const float*)d_in[7];
    const float* w3  = (const float*)d_in[8];
    const float* g3  = (const float*)d_in[9];
    const float* be3 = (const float*)d_in[10];
    const float* w4  = (const float*)d_in[11];
    const float* b4  = (const float*)d_in[12];
    const float* wb  = (const float*)d_in[13];
    const float* bn_g = (const float*)d_in[14];
    const float* bn_b = (const float*)d_in[15];

    f16* scores = (f16*)d_ws;                             // 4 MB
    f16* wbtA   = (f16*)((char*)d_ws + (4u << 20));       // 128 KB

    k_scores<<<512, 256, 0, stream>>>(xyz, w1, g1, be1, w2, g2, be2,
                                      w3, g3, be3, w4, b4, wb, wbtA, scores);
    k_main<<<512, 1024, 0, stream>>>(features, scores, wbtA, bn_g, bn_b,
                                     (float*)d_out);
}

// Round 4
// 174.921 us; speedup vs baseline: 1.4681x; 1.4681x over previous
//
#include <hip/hip_runtime.h>
#include <hip/hip_bf16.h>

typedef _Float16 f16;
typedef __attribute__((ext_vector_type(2))) _Float16 f16x2;
typedef __attribute__((ext_vector_type(8))) _Float16 f16x8;
typedef __attribute__((ext_vector_type(16))) float f32x16;

#define BNSCL 0.9999950000375f   /* 1/sqrt(1+1e-5) */

// ---------------------------------------------------------------------------
// Kernel 1: per-point scores MLP + softmax (weights in LDS, 2 pts/thread),
// output f16x8 per point. Fused: blocks < 256 also build wbtA = weight bank
// in MFMA A-fragment order, f16:
//   wbtA[((ot*64 + ks)*64 + lane)*8 + j] = wb[c'][m=j][o]
//   with c' = ks*2 + (lane>>5), o = ot*32 + (lane&31).
// ---------------------------------------------------------------------------
__global__ __launch_bounds__(256) void k_scores(
    const float* __restrict__ xyz,
    const float* __restrict__ w1, const float* __restrict__ g1, const float* __restrict__ be1,
    const float* __restrict__ w2, const float* __restrict__ g2, const float* __restrict__ be2,
    const float* __restrict__ w3, const float* __restrict__ g3, const float* __restrict__ be3,
    const float* __restrict__ w4, const float* __restrict__ b4,
    const float* __restrict__ wb, f16* __restrict__ wbtA,
    f16* __restrict__ scores)
{
    __shared__ float lw[856];
    const int tid = threadIdx.x;

    // fused weight-bank fragment-order transpose (1 elem/thread, blocks 0-255)
    if (blockIdx.x < 256) {
        int idx = blockIdx.x * 256 + tid;       // 0..65535
        int j    = idx & 7;
        int lane = (idx >> 3) & 63;
        int ks   = (idx >> 9) & 63;
        int ot   = idx >> 15;
        int cp   = ks * 2 + (lane >> 5);        // 0..127
        int o    = ot * 32 + (lane & 31);
        wbtA[idx] = (f16)wb[(cp * 8 + j) * 64 + o];
    }

    if (tid < 112) lw[tid] = w1[tid];
    lw[112 + tid] = w2[tid];
    lw[368 + tid] = w3[tid];
    if (tid < 128) lw[624 + tid] = w4[tid];
    if (tid < 8)   lw[752 + tid] = b4[tid];
    if (tid < 16) {
        lw[760 + tid] = g1[tid] * BNSCL;  lw[776 + tid] = be1[tid];
        lw[792 + tid] = g2[tid] * BNSCL;  lw[808 + tid] = be2[tid];
        lw[824 + tid] = g3[tid] * BNSCL;  lw[840 + tid] = be3[tid];
    }
    __syncthreads();

    float in7[2][7], h1[2][16], h2[2][16], s[2][8];

#pragma unroll
    for (int q = 0; q < 2; ++q) {
        int g = blockIdx.x * 512 + q * 256 + tid;
        int b = g >> 15;
        int p = g & 32767;
        int pc = p & ~31;
        const float* xb = xyz + (size_t)b * 98304;
        float cx = xb[pc], cy = xb[32768 + pc], cz = xb[65536 + pc];
        float dx = xb[p] - cx, dy = xb[32768 + p] - cy, dz = xb[65536 + p] - cz;
        in7[q][0] = cx; in7[q][1] = cy; in7[q][2] = cz;
        in7[q][3] = dx; in7[q][4] = dy; in7[q][5] = dz;
        in7[q][6] = sqrtf(dx * dx + dy * dy + dz * dz);
    }

#pragma unroll
    for (int o = 0; o < 16; ++o) {
        float a0 = 0.f, a1 = 0.f;
#pragma unroll
        for (int c = 0; c < 7; ++c) {
            float w = lw[o * 7 + c];
            a0 += w * in7[0][c]; a1 += w * in7[1][c];
        }
        float gs = lw[760 + o], bb = lw[776 + o];
        h1[0][o] = fmaxf(a0 * gs + bb, 0.f);
        h1[1][o] = fmaxf(a1 * gs + bb, 0.f);
    }
#pragma unroll
    for (int o = 0; o < 16; ++o) {
        float a0 = 0.f, a1 = 0.f;
#pragma unroll
        for (int c = 0; c < 16; ++c) {
            float w = lw[112 + o * 16 + c];
            a0 += w * h1[0][c]; a1 += w * h1[1][c];
        }
        float gs = lw[792 + o], bb = lw[808 + o];
        h2[0][o] = fmaxf(a0 * gs + bb, 0.f);
        h2[1][o] = fmaxf(a1 * gs + bb, 0.f);
    }
#pragma unroll
    for (int o = 0; o < 16; ++o) {
        float a0 = 0.f, a1 = 0.f;
#pragma unroll
        for (int c = 0; c < 16; ++c) {
            float w = lw[368 + o * 16 + c];
            a0 += w * h2[0][c]; a1 += w * h2[1][c];
        }
        float gs = lw[824 + o], bb = lw[840 + o];
        h1[0][o] = fmaxf(a0 * gs + bb, 0.f);
        h1[1][o] = fmaxf(a1 * gs + bb, 0.f);
    }
#pragma unroll
    for (int o = 0; o < 8; ++o) {
        float bb = lw[752 + o];
        float a0 = bb, a1 = bb;
#pragma unroll
        for (int c = 0; c < 16; ++c) {
            float w = lw[624 + o * 16 + c];
            a0 += w * h1[0][c]; a1 += w * h1[1][c];
        }
        s[0][o] = a0; s[1][o] = a1;
    }

#pragma unroll
    for (int q = 0; q < 2; ++q) {
        int g = blockIdx.x * 512 + q * 256 + tid;
        float mx = s[q][0];
#pragma unroll
        for (int i = 1; i < 8; ++i) mx = fmaxf(mx, s[q][i]);
        float sum = 0.f;
#pragma unroll
        for (int i = 0; i < 8; ++i) { s[q][i] = __expf(s[q][i] - mx); sum += s[q][i]; }
        float inv = 1.f / sum;
        f16x8 o8;
#pragma unroll
        for (int i = 0; i < 8; ++i) o8[i] = (f16)(s[q][i] * inv);
        *(f16x8*)(scores + (size_t)g * 8) = o8;
    }
}

// ---------------------------------------------------------------------------
// Kernel 2: main einsum, 32x32x16 f16 MFMA.
// THIS ROUND: feat staged via global_load_lds DMA with counted vmcnt.
// Round-3 spilled (launch_bounds(1024,8) -> 64-VGPR cap incl. accum; WRITE
// 173 MB of scratch). Round 1-2 showed the compiler defeats register-level
// prefetch pipelines (sinks loads to uses; VGPR 52). Fix: back to 512-thr /
// 2-blocks-per-CU, and stage feat by DMA: fbuf[4][2][512] f32 quad-buffer
// (16 KB; 64+16=80 KB LDS -> still 2 blocks/CU). KEY: each wave reads ONLY
// the 512 B it stages itself (its own 64-pt window, rows 2kk/2kk+1), so feat
// staging needs NO barriers - per-wave counted vmcnt is the only sync.
// Pipeline: prologue stages kk=0..2 (6 loads in flight, carried across the
// weights barrier - raw s_barrier, no drain); step kk issues stage(kk+3)
// into buf[(kk+3)&3] (disjoint from buf[kk&3] being read; literal indices =>
// exact alias analysis preserves issue order), waits vmcnt(6), computes.
// vmcnt never drains to 0 in steady state (T4). BN loads fenced after loop
// by sched_barrier(0) so no stray VMEM perturbs the counts.
// ---------------------------------------------------------------------------
__global__ __launch_bounds__(512, 4) void k_main(
    const float* __restrict__ feat,
    const f16* __restrict__ scores,
    const f16* __restrict__ wbtA,
    const float* __restrict__ bn_g, const float* __restrict__ bn_b,
    float* __restrict__ out)
{
    __shared__ __align__(16) f16 lwb[32768];        // 64 KB weights
    __shared__ __align__(16) float fbuf[4][2][512]; // 16 KB feat quad-buffer

    const int tid  = threadIdx.x;
    const int lane = tid & 63;
    const int wave = tid >> 6;          // 0..7
    const int l31  = lane & 31;
    const int lh   = lane >> 5;         // 0..1
    const int w64  = wave * 64;

    const int ot = blockIdx.x >> 9;             // 0..1 (o-tile half)
    const int g  = blockIdx.x & 511;            // point-group
    const int pblock = g * 512;                 // global point base
    const int b    = pblock >> 15;
    const int pt0  = (pblock & 32767) + w64;    // within-batch, 32-aligned
    const int pc0  = pt0 + l31;
    const int pc1  = pc0 + 32;

    const float* fb = feat + (size_t)b * 2097152;    // (64, 32768)
    // per-lane DMA source base: point (pblock&32767) + wave*64 + lane, row 0
    const float* gsrc0 = fb + (pblock & 32767) + w64 + lane;

    // ---- stage this ot's 64 KB of fragment-ordered weights into LDS ----
    const f16* src = wbtA + ((size_t)ot << 15);      // 32768 f16
#pragma unroll
    for (int it = 0; it < 8; ++it) {
        int idx = it * 512 + tid;                    // 0..4095 16B-chunks
        *(int4*)&lwb[idx << 3] = *(const int4*)&src[idx << 3];
    }

    // ---- scores: load + extract to registers (consumed before loop) ----
    const int gpt = pblock + w64 + l31;
    f16x8 sv0 = *(const f16x8*)(scores + (size_t)gpt * 8);
    f16x8 sv1 = *(const f16x8*)(scores + (size_t)(gpt + 32) * 8);
    const f16x2 s0a = {sv0[0], sv0[1]}, s0b = {sv0[2], sv0[3]},
                s0c = {sv0[4], sv0[5]}, s0d = {sv0[6], sv0[7]};
    const f16x2 s1a = {sv1[0], sv1[1]}, s1b = {sv1[2], sv1[3]},
                s1c = {sv1[4], sv1[5]}, s1d = {sv1[6], sv1[7]};

    f32x16 acc0 = {}, acc1 = {};
    const f16* Alds = lwb + (lane << 3);             // lane's 16B slot

// DMA one kk-step's feat tile (rows 2kk, 2kk+1; this wave's 64 points) into
// fbuf[kk&3]. Wave-uniform LDS dest + lane*4; per-lane global src.
#define STAGE(t)                                                               \
    {                                                                          \
        __builtin_amdgcn_global_load_lds(                                      \
            (const __attribute__((address_space(1))) void*)                    \
                (gsrc0 + ((size_t)(2 * (t)) << 15)),                           \
            (__attribute__((address_space(3))) void*)&fbuf[(t) & 3][0][w64],   \
            4, 0, 0);                                                          \
        __builtin_amdgcn_global_load_lds(                                      \
            (const __attribute__((address_space(1))) void*)                    \
                (gsrc0 + ((size_t)(2 * (t) + 1) << 15)),                       \
            (__attribute__((address_space(3))) void*)&fbuf[(t) & 3][1][w64],   \
            4, 0, 0);                                                          \
    }

#define WAITV(n) asm volatile("s_waitcnt vmcnt(" #n ")" ::: "memory")

    // keep pre-loop loads/extracts above; then prologue DMA kk=0..2
    __builtin_amdgcn_sched_barrier(0);
    STAGE(0); STAGE(1); STAGE(2);

    // weights visible to all waves; prologue DMAs stay in flight (raw barrier)
    asm volatile("s_waitcnt lgkmcnt(0)" ::: "memory");
    __builtin_amdgcn_s_barrier();

#define KSTEP(kk, N)                                                           \
    {                                                                          \
        if ((kk) + 3 <= 31) { STAGE((kk) + 3); }                               \
        WAITV(N);                                                              \
        f16x8 aD = *(const f16x8*)(Alds + ((size_t)(kk) << 9));                \
        f16x8 aR = *(const f16x8*)(Alds + ((size_t)((kk) + 32) << 9));         \
        const float* frow = fbuf[(kk) & 3][lh];                                \
        float fv0 = frow[w64 + l31], fv1 = frow[w64 + l31 + 32];               \
        float fc0 = frow[w64],       fc1 = frow[w64 + 32];                     \
        f16 hR0 = (f16)fv0,          hR1 = (f16)fv1;                           \
        f16 hD0 = (f16)(fv0 - fc0),  hD1 = (f16)(fv1 - fc1);                   \
        f16x2 fR0 = {hR0, hR0}, fR1 = {hR1, hR1};                              \
        f16x2 fD0 = {hD0, hD0}, fD1 = {hD1, hD1};                              \
        f16x2 d0a = fD0 * s0a, d0b = fD0 * s0b, d0c = fD0 * s0c, d0d = fD0 * s0d; \
        f16x2 d1a = fD1 * s1a, d1b = fD1 * s1b, d1c = fD1 * s1c, d1d = fD1 * s1d; \
        f16x2 r0a = fR0 * s0a, r0b = fR0 * s0b, r0c = fR0 * s0c, r0d = fR0 * s0d; \
        f16x2 r1a = fR1 * s1a, r1b = fR1 * s1b, r1c = fR1 * s1c, r1d = fR1 * s1d; \
        f16x8 bD0 = {d0a[0],d0a[1],d0b[0],d0b[1],d0c[0],d0c[1],d0d[0],d0d[1]}; \
        f16x8 bD1 = {d1a[0],d1a[1],d1b[0],d1b[1],d1c[0],d1c[1],d1d[0],d1d[1]}; \
        f16x8 bR0 = {r0a[0],r0a[1],r0b[0],r0b[1],r0c[0],r0c[1],r0d[0],r0d[1]}; \
        f16x8 bR1 = {r1a[0],r1a[1],r1b[0],r1b[1],r1c[0],r1c[1],r1d[0],r1d[1]}; \
        acc0 = __builtin_amdgcn_mfma_f32_32x32x16_f16(aD, bD0, acc0, 0, 0, 0); \
        acc1 = __builtin_amdgcn_mfma_f32_32x32x16_f16(aD, bD1, acc1, 0, 0, 0); \
        acc0 = __builtin_amdgcn_mfma_f32_32x32x16_f16(aR, bR0, acc0, 0, 0, 0); \
        acc1 = __builtin_amdgcn_mfma_f32_32x32x16_f16(aR, bR1, acc1, 0, 0, 0); \
    }

#define KS4(b0) KSTEP(b0, 6) KSTEP((b0)+1, 6) KSTEP((b0)+2, 6) KSTEP((b0)+3, 6)
    KS4(0)  KS4(4)  KS4(8)  KS4(12)
    KS4(16) KS4(20) KS4(24)
    KSTEP(28, 6) KSTEP(29, 4) KSTEP(30, 2) KSTEP(31, 0)
#undef KS4
#undef KSTEP
#undef STAGE
#undef WAITV

    // fence: keep epilogue VMEM (bn loads, stores) out of the counted region
    __builtin_amdgcn_sched_barrier(0);

    // ---------------- epilogue: BN + ReLU + coalesced store ------------------
    // C layout: col = lane&31, row = (r&3) + 8*(r>>2) + 4*lh
#pragma unroll
    for (int r = 0; r < 16; ++r) {
        int o = ot * 32 + (r & 3) + ((r >> 2) << 3) + (lh << 2);
        float gs = bn_g[o] * BNSCL, bb = bn_b[o];
        size_t row = (size_t)(b * 64 + o) << 15;
        out[row + pc0] = fmaxf(acc0[r] * gs + bb, 0.f);
        out[row + pc1] = fmaxf(acc1[r] * gs + bb, 0.f);
    }
}

// ---------------------------------------------------------------------------
extern "C" void kernel_launch(void* const* d_in, const int* in_sizes, int n_in,
                              void* d_out, int out_size, void* d_ws, size_t ws_size,
                              hipStream_t stream)
{
    const float* features = (const float*)d_in[0];
    const float* xyz      = (const float*)d_in[1];
    const float* w1  = (const float*)d_in[2];
    const float* g1  = (const float*)d_in[3];
    const float* be1 = (const float*)d_in[4];
    const float* w2  = (const float*)d_in[5];
    const float* g2  = (const float*)d_in[6];
    const float* be2 = (const float*)d_in[7];
    const float* w3  = (const float*)d_in[8];
    const float* g3  = (const float*)d_in[9];
    const float* be3 = (const float*)d_in[10];
    const float* w4  = (const float*)d_in[11];
    const float* b4  = (const float*)d_in[12];
    const float* wb  = (const float*)d_in[13];
    const float* bn_g = (const float*)d_in[14];
    const float* bn_b = (const float*)d_in[15];

    f16* scores = (f16*)d_ws;                             // 4 MB
    f16* wbtA   = (f16*)((char*)d_ws + (4u << 20));       // 128 KB

    k_scores<<<512, 256, 0, stream>>>(xyz, w1, g1, be1, w2, g2, be2,
                                      w3, g3, be3, w4, b4, wb, wbtA, scores);
    k_main<<<1024, 512, 0, stream>>>(features, scores, wbtA, bn_g, bn_b,
                                     (float*)d_out);
}